// Round 4
// baseline (365.306 us; speedup 1.0000x reference)
//
#include <hip/hip_runtime.h>
#include <cmath>

typedef unsigned short u16;
typedef __bf16 bf16x8 __attribute__((ext_vector_type(8)));
typedef float f32x4 __attribute__((ext_vector_type(4)));
typedef float float4v __attribute__((ext_vector_type(4)));
typedef u16 ushort4v __attribute__((ext_vector_type(4)));
typedef u16 ushort8v __attribute__((ext_vector_type(8)));

#define DIMC 768
#define NP 196
#define MTOT 6272         // 32*196
#define HIDC 3072
#define LAMC 3.5f

__device__ const float C14d[14] = {
  1.0f, 0.9009688679024191f, 0.6234898018587336f, 0.22252093395631445f,
  -0.22252093395631445f, -0.6234898018587336f, -0.9009688679024191f, -1.0f,
  -0.9009688679024191f, -0.6234898018587336f, -0.22252093395631445f,
  0.22252093395631445f, 0.6234898018587336f, 0.9009688679024191f
};
__device__ const float S14d[14] = {
  0.0f, 0.43388373911755823f, 0.7818314824680298f, 0.9749279121818236f,
  0.9749279121818236f, 0.7818314824680298f, 0.43388373911755823f, 0.0f,
  -0.43388373911755823f, -0.7818314824680298f, -0.9749279121818236f,
  -0.9749279121818236f, -0.7818314824680298f, -0.43388373911755823f
};

__device__ __forceinline__ u16 f2bf(float f) {
  unsigned u = __builtin_bit_cast(unsigned, f);
  unsigned r = u + 0x7FFFu + ((u >> 16) & 1u);
  return (u16)(r >> 16);
}
__device__ __forceinline__ float bf2f(u16 u) {
  return __builtin_bit_cast(float, (unsigned)u << 16);
}

typedef const __attribute__((address_space(1))) u16* gas_p;
typedef __attribute__((address_space(3))) u16* las_p;
__device__ __forceinline__ void gl16(const u16* g, u16* l) {
  __builtin_amdgcn_global_load_lds((gas_p)g, (las_p)l, 16, 0, 0);
}

// ---------------- build fragment-ordered DFT matrices F / G ----------------
__global__ __launch_bounds__(256) void initfg_k(u16* __restrict__ Ff, u16* __restrict__ Gf) {
  int idx = blockIdx.x * 256 + threadIdx.x;
  if (idx < 50176) {                       // Ff: 14*7*64*8
    int j = idx & 7, lane = (idx >> 3) & 63;
    int mk = idx >> 9, k0 = mk % 7, m0 = mk / 7;
    int s = m0 * 16 + (lane & 15);
    int q = k0 * 32 + (lane >> 4) * 8 + j;
    float v = 0.f;
    if (q < 196) {
      int kr = s >> 4, f = (s >> 1) & 7, r = q / 14, c = q % 14;
      int th = (kr * r + f * c) % 14;
      v = (s & 1) ? -S14d[th] : C14d[th];
    }
    Ff[idx] = f2bf(v);
  } else if (idx < 50176 + 46592) {        // Gf: 13*7*64*8
    int t = idx - 50176;
    int j = t & 7, lane = (t >> 3) & 63;
    int pk = t >> 9, k0 = pk % 7, p0 = pk / 7;
    int p = p0 * 16 + (lane & 15);
    int s = k0 * 32 + (lane >> 4) * 8 + j;
    float v = 0.f;
    if (p < 196) {
      int kr = s >> 4, f = (s >> 1) & 7, r = p / 14, c = p % 14;
      int th = (kr * r + f * c) % 14;
      float w = (f == 0 || f == 7) ? 1.f : 2.f;
      v = (w * (1.f / 196.f)) * ((s & 1) ? -S14d[th] : C14d[th]);
    }
    Gf[t] = f2bf(v);
  }
}

// ---------------- fused weight convert ----------------
__global__ __launch_bounds__(256) void cvtw_k(
    const float* __restrict__ w0, const float* __restrict__ w1,
    const float* __restrict__ w2, const float* __restrict__ w3,
    u16* __restrict__ o0, u16* __restrict__ o1,
    u16* __restrict__ o2, u16* __restrict__ o3) {
  int idx = blockIdx.x * 256 + threadIdx.x;
  const float* s; u16* d; int base;
  if (idx < 147456)      { s = w0; d = o0; base = 0; }
  else if (idx < 294912) { s = w1; d = o1; base = 147456; }
  else if (idx < 884736) { s = w2; d = o2; base = 294912; }
  else                   { s = w3; d = o3; base = 884736; }
  int i4 = (idx - base) * 4;
  float4v v = *(const float4v*)(s + i4);
  ushort4v o;
#pragma unroll
  for (int j = 0; j < 4; ++j) o[j] = f2bf(v[j]);
  *(ushort4v*)(d + i4) = o;
}

__global__ __launch_bounds__(256) void cvt4_k(const float* __restrict__ s,
                                              u16* __restrict__ d, int n4) {
  int idx = blockIdx.x * 256 + threadIdx.x;
  if (idx >= n4) return;
  int i4 = idx * 4;
  float4v v = *(const float4v*)(s + i4);
  ushort4v o;
#pragma unroll
  for (int j = 0; j < 4; ++j) o[j] = f2bf(v[j]);
  *(ushort4v*)(d + i4) = o;
}

// ---------------- BN-normalize + convert to bf16 ----------------
__global__ __launch_bounds__(256) void bncvt_k(const float* __restrict__ s,
    const float* __restrict__ sc, const float* __restrict__ sh,
    u16* __restrict__ d, int n4) {
  int idx = blockIdx.x * 256 + threadIdx.x;
  if (idx >= n4) return;
  int i4 = idx * 4;
  int c = i4 % DIMC;
  float4v v = *(const float4v*)(s + i4);
  float4v a = *(const float4v*)(sc + c);
  float4v b = *(const float4v*)(sh + c);
  v = v * a + b;
  ushort4v o;
#pragma unroll
  for (int j = 0; j < 4; ++j) o[j] = f2bf(v[j]);
  *(ushort4v*)(d + i4) = o;
}

// ---------------- 128x128 bf16 MFMA GEMM, fragment-ordered LDS ----------------
// Staging lane fetches global (row = lane&15, kslot = lane>>4); the linear
// global_load_lds write then leaves each 16-row chunk already in MFMA fragment
// order, so reads are chunk_base + lane*16B: linear, conflict-free.
// EPI 0: f32 transpose-write  vxt[(b*768+n)*196+np], m=b*196+np
// EPI 1: f32 C[m*Nr+n] = acc + bias[n] + res[m*Nr+n]
// EPI 2: bf16 C[m*Nr+n] = gelu_exact(acc + bias[n])
// EPI 3: bf16 partial C[kz*MTOT*DIMC + m*Nr+n] = acc     (split-K)
template<int EPI, int SPLIT = 0>
__global__ __launch_bounds__(256) void gemm_k(
    const u16* __restrict__ A, const u16* __restrict__ Bw,
    const float* __restrict__ bias, const float* __restrict__ res,
    void* __restrict__ Cp, int Nr, int Kr, int ld) {
  __shared__ __attribute__((aligned(16))) u16 As[128 * 32];
  __shared__ __attribute__((aligned(16))) u16 Bs[128 * 32];
  const int t = threadIdx.x;
  const int wid = t >> 6, lane = t & 63;
  const int bn = blockIdx.x * 128, bm = blockIdx.y * 128;
  const int kz = SPLIT ? blockIdx.z : 0;
  const int wm = (wid >> 1) * 64, wn = (wid & 1) * 64;
  const int l15 = lane & 15, l4 = lane >> 4;

  f32x4 acc[4][4];
#pragma unroll
  for (int a = 0; a < 4; ++a)
#pragma unroll
    for (int b2 = 0; b2 < 4; ++b2) acc[a][b2] = (f32x4){0.f, 0.f, 0.f, 0.f};

  // fragment-order staging source
  const u16* gA0 = A + (size_t)(bm + wid * 16 + l15) * ld + (size_t)kz * Kr + l4 * 8;
  const u16* gB0 = Bw + (size_t)(bn + wid * 16 + l15) * ld + (size_t)kz * Kr + l4 * 8;
  u16* lA = As + wid * 512;
  u16* lB = Bs + wid * 512;

  for (int k0 = 0; k0 < Kr; k0 += 32) {
    gl16(gA0 + k0, lA);
    gl16(gA0 + (size_t)64 * ld + k0, lA + 2048);
    gl16(gB0 + k0, lB);
    gl16(gB0 + (size_t)64 * ld + k0, lB + 2048);
    __syncthreads();

    bf16x8 af[4], bfv[4];
#pragma unroll
    for (int mb = 0; mb < 4; ++mb)
      af[mb] = *(const bf16x8*)&As[((wid >> 1) * 4 + mb) * 512 + lane * 8];
#pragma unroll
    for (int nb = 0; nb < 4; ++nb)
      bfv[nb] = *(const bf16x8*)&Bs[((wid & 1) * 4 + nb) * 512 + lane * 8];
#pragma unroll
    for (int mb = 0; mb < 4; ++mb)
#pragma unroll
      for (int nb = 0; nb < 4; ++nb)
        acc[mb][nb] = __builtin_amdgcn_mfma_f32_16x16x32_bf16(af[mb], bfv[nb], acc[mb][nb], 0, 0, 0);
    __syncthreads();
  }

#pragma unroll
  for (int mb = 0; mb < 4; ++mb) {
#pragma unroll
    for (int nb = 0; nb < 4; ++nb) {
      int n = bn + wn + nb * 16 + l15;
#pragma unroll
      for (int r = 0; r < 4; ++r) {
        int m = bm + wm + mb * 16 + l4 * 4 + r;
        float v = acc[mb][nb][r];
        if (EPI == 0) {
          int bb = m / 196, np = m - bb * 196;
          ((float*)Cp)[((size_t)bb * DIMC + n) * 196 + np] = v;
        } else if (EPI == 1) {
          ((float*)Cp)[(size_t)m * Nr + n] = v + bias[n] + res[(size_t)m * Nr + n];
        } else if (EPI == 2) {
          float vb = v + bias[n];
          float ge = 0.5f * vb * (1.f + erff(vb * 0.70710678118654752f));
          ((u16*)Cp)[(size_t)m * Nr + n] = f2bf(ge);
        } else {
          ((u16*)Cp)[(size_t)kz * MTOT * DIMC + (size_t)m * Nr + n] = f2bf(v);
        }
      }
    }
  }
}

// ---------------- split-K reduce: out = sum(partials) + bias + res ----------------
__global__ __launch_bounds__(256) void redc_k(const u16* __restrict__ p,
    const float* __restrict__ bias, const float* __restrict__ res,
    float* __restrict__ out) {
  int idx = blockIdx.x * 256 + threadIdx.x;
  size_t i4 = (size_t)idx * 4;
  const size_t S = (size_t)MTOT * DIMC;
  ushort4v p0 = *(const ushort4v*)(p + i4);
  ushort4v p1 = *(const ushort4v*)(p + S + i4);
  ushort4v p2 = *(const ushort4v*)(p + 2 * S + i4);
  ushort4v p3 = *(const ushort4v*)(p + 3 * S + i4);
  float4v r = *(const float4v*)(res + i4);
  int c = (int)(i4 % DIMC);
  float4v bs = *(const float4v*)(bias + c);
  float4v o;
#pragma unroll
  for (int j = 0; j < 4; ++j)
    o[j] = bf2f(p0[j]) + bf2f(p1[j]) + bf2f(p2[j]) + bf2f(p3[j]) + bs[j] + r[j];
  *(float4v*)(out + i4) = o;
}

// ---------------- BN stats (deterministic 2-stage) ----------------
__global__ __launch_bounds__(256) void stats_part_k(const float* __restrict__ A,
                                                    float* __restrict__ part) {
  int blk = blockIdx.x, t = threadIdx.x;
  float s0a = 0, s0b = 0, s0c = 0, s1a = 0, s1b = 0, s1c = 0;
  const float* base = A + (size_t)blk * 64 * DIMC;
  for (int r = 0; r < 64; ++r) {
    const float* row = base + (size_t)r * DIMC;
    float v0 = row[t], v1 = row[t + 256], v2 = row[t + 512];
    s0a += v0; s1a += v0 * v0;
    s0b += v1; s1b += v1 * v1;
    s0c += v2; s1c += v2 * v2;
  }
  part[(size_t)blk * DIMC + t] = s0a;
  part[(size_t)blk * DIMC + t + 256] = s0b;
  part[(size_t)blk * DIMC + t + 512] = s0c;
  float* p2 = part + 98 * DIMC;
  p2[(size_t)blk * DIMC + t] = s1a;
  p2[(size_t)blk * DIMC + t + 256] = s1b;
  p2[(size_t)blk * DIMC + t + 512] = s1c;
}

__global__ __launch_bounds__(256) void stats_fin_k(const float* __restrict__ part,
    const float* __restrict__ gam, const float* __restrict__ bet,
    float* __restrict__ scale, float* __restrict__ shift) {
  int c = blockIdx.x * 256 + threadIdx.x;
  if (c >= DIMC) return;
  float S = 0.f, Q = 0.f;
  for (int b = 0; b < 98; ++b) {
    S += part[(size_t)b * DIMC + c];
    Q += part[(size_t)(98 + b) * DIMC + c];
  }
  float m = S * (1.0f / 6272.0f);
  float v = Q * (1.0f / 6272.0f) - m * m;
  v = fmaxf(v, 0.f);
  float rs = rsqrtf(v + 1e-5f);
  float sc = gam[c] * rs;
  scale[c] = sc;
  shift[c] = bet[c] - m * sc;
}

// ---------------- MFMA screen: max_i max_p |u_i| per tile, flag > 3.4 ----------
__global__ __launch_bounds__(64) void checkmfma_k(
    const float* __restrict__ vxt, const float* __restrict__ kern,
    const u16* __restrict__ Ff, const u16* __restrict__ Gf,
    int* __restrict__ cnt, int* __restrict__ wl) {
  __shared__ float xf[16 * 228];
  const int lane = threadIdx.x;
  const int wgb = blockIdx.x;
  const int g = wgb >> 1, bhalf = wgb & 1;
  const int tl = lane & 15, h = lane >> 4;
  const float* xbase = vxt + ((size_t)(bhalf * 16 + tl) * DIMC + g) * 196;

  bf16x8 Bx[7];
#pragma unroll
  for (int k0 = 0; k0 < 7; ++k0) {
    int q0 = k0 * 32 + h * 8;
    ushort8v tv;
    if (k0 < 6) {
      float4v f0 = *(const float4v*)(xbase + q0);
      float4v f1 = *(const float4v*)(xbase + q0 + 4);
#pragma unroll
      for (int j = 0; j < 4; ++j) { tv[j] = f2bf(f0[j]); tv[j + 4] = f2bf(f1[j]); }
    } else {
#pragma unroll
      for (int j = 0; j < 8; ++j) {
        int q = q0 + j;
        tv[j] = (q < 196) ? f2bf(xbase[q]) : (u16)0;
      }
    }
    Bx[k0] = __builtin_bit_cast(bf16x8, tv);
  }

  for (int m0 = 0; m0 < 14; ++m0) {
    f32x4 acc = (f32x4){0.f, 0.f, 0.f, 0.f};
#pragma unroll
    for (int k0 = 0; k0 < 7; ++k0) {
      bf16x8 Af = __builtin_bit_cast(bf16x8,
          *(const ushort8v*)(Ff + ((size_t)(m0 * 7 + k0) * 64 + lane) * 8));
      acc = __builtin_amdgcn_mfma_f32_16x16x32_bf16(Af, Bx[k0], acc, 0, 0, 0);
    }
    *(f32x4*)&xf[tl * 228 + m0 * 16 + h * 4] = acc;
  }

  bf16x8 By[5][7];
#pragma unroll
  for (int i = 0; i < 5; ++i) {
    const float* kb = kern + ((size_t)g * 5 + i) * 224;
#pragma unroll
    for (int k0 = 0; k0 < 7; ++k0) {
      f32x4 x0 = *(const f32x4*)&xf[tl * 228 + k0 * 32 + h * 8];
      f32x4 x1 = *(const f32x4*)&xf[tl * 228 + k0 * 32 + h * 8 + 4];
      int mb = k0 * 16 + h * 4;
      float2 ka = *(const float2*)(kb + (mb + 0) * 2);
      float2 kc = *(const float2*)(kb + (mb + 1) * 2);
      float2 ke = *(const float2*)(kb + (mb + 2) * 2);
      float2 kg = *(const float2*)(kb + (mb + 3) * 2);
      ushort8v tv;
      tv[0] = f2bf(ka.x * x0[0] - ka.y * x0[1]);
      tv[1] = f2bf(ka.x * x0[1] + ka.y * x0[0]);
      tv[2] = f2bf(kc.x * x0[2] - kc.y * x0[3]);
      tv[3] = f2bf(kc.x * x0[3] + kc.y * x0[2]);
      tv[4] = f2bf(ke.x * x1[0] - ke.y * x1[1]);
      tv[5] = f2bf(ke.x * x1[1] + ke.y * x1[0]);
      tv[6] = f2bf(kg.x * x1[2] - kg.y * x1[3]);
      tv[7] = f2bf(kg.x * x1[3] + kg.y * x1[2]);
      By[i][k0] = __builtin_bit_cast(bf16x8, tv);
    }
  }

  float vmax = 0.f;
  for (int p0 = 0; p0 < 13; ++p0) {
    f32x4 a0 = (f32x4){0.f, 0.f, 0.f, 0.f};
    f32x4 a1 = a0, a2 = a0, a3 = a0, a4 = a0;
#pragma unroll
    for (int k0 = 0; k0 < 7; ++k0) {
      bf16x8 Ag = __builtin_bit_cast(bf16x8,
          *(const ushort8v*)(Gf + ((size_t)(p0 * 7 + k0) * 64 + lane) * 8));
      a0 = __builtin_amdgcn_mfma_f32_16x16x32_bf16(Ag, By[0][k0], a0, 0, 0, 0);
      a1 = __builtin_amdgcn_mfma_f32_16x16x32_bf16(Ag, By[1][k0], a1, 0, 0, 0);
      a2 = __builtin_amdgcn_mfma_f32_16x16x32_bf16(Ag, By[2][k0], a2, 0, 0, 0);
      a3 = __builtin_amdgcn_mfma_f32_16x16x32_bf16(Ag, By[3][k0], a3, 0, 0, 0);
      a4 = __builtin_amdgcn_mfma_f32_16x16x32_bf16(Ag, By[4][k0], a4, 0, 0, 0);
    }
#pragma unroll
    for (int r = 0; r < 4; ++r) {
      vmax = fmaxf(vmax, fabsf(a0[r]));
      vmax = fmaxf(vmax, fabsf(a1[r]));
      vmax = fmaxf(vmax, fabsf(a2[r]));
      vmax = fmaxf(vmax, fabsf(a3[r]));
      vmax = fmaxf(vmax, fabsf(a4[r]));
    }
  }
  vmax = fmaxf(vmax, __shfl_xor(vmax, 16));
  vmax = fmaxf(vmax, __shfl_xor(vmax, 32));
  if (lane < 16 && vmax > (LAMC - 0.1f)) {
    int idx = atomicAdd(cnt, 1);
    wl[idx] = g * 32 + bhalf * 16 + lane;
  }
}

// ---------------- full ISTA for flagged tiles (fp32, exact) ----------------
__global__ __launch_bounds__(64) void slow_k(
    const float* __restrict__ vxt, const float* __restrict__ kern,
    const float* __restrict__ kern2, const float* __restrict__ Lbuf,
    const int* __restrict__ cnt, const int* __restrict__ wl,
    float* __restrict__ outp) {
  const int t = threadIdx.x;
  __shared__ float TC[196], TSn[196];
  __shared__ float xs[196];
  __shared__ float t1R[112], t1I[112];
  __shared__ float t2R[112], t2I[112];
  __shared__ float zr[112], zi[112];
  __shared__ float kR[5][112], kI[5][112];
  __shared__ float uu[5][196];
  __shared__ float ss[5][196];
  __shared__ float k2R[112], k2I[112];

  for (int i = t; i < 196; i += 64) {
    int a = i / 14, c = i - (i / 14) * 14;
    int m = (a * c) % 14;
    TC[i] = C14d[m]; TSn[i] = S14d[m];
  }
  const int ntile = *cnt;

  auto rowsFwd = [&](const float* xsrc) {
    for (int i = t; i < 112; i += 64) {
      int r = i >> 3, f = i & 7;
      const float* xp = xsrc + r * 14;
      const float* tc = &TC[f * 14]; const float* tsn = &TSn[f * 14];
      float ar = 0.f, ai = 0.f;
#pragma unroll
      for (int c = 0; c < 14; ++c) { float xv = xp[c]; ar += xv * tc[c]; ai -= xv * tsn[c]; }
      t1R[i] = ar; t1I[i] = ai;
    }
    __syncthreads();
  };
  auto colsFwd = [&](float* oR, float* oI) {
    for (int i = t; i < 112; i += 64) {
      int kr = i >> 3, f = i & 7;
      const float* tc = &TC[kr * 14]; const float* tsn = &TSn[kr * 14];
      float br = 0.f, bi = 0.f;
#pragma unroll
      for (int r = 0; r < 14; ++r) {
        float xr = t1R[r * 8 + f], xi = t1I[r * 8 + f];
        br += tc[r] * xr + tsn[r] * xi;
        bi += tc[r] * xi - tsn[r] * xr;
      }
      oR[i] = br; oI[i] = bi;
    }
    __syncthreads();
  };
  auto colsInv = [&]() {
    for (int i = t; i < 112; i += 64) {
      int r = i >> 3, f = i & 7;
      const float* tc = &TC[r * 14]; const float* tsn = &TSn[r * 14];
      float br = 0.f, bi = 0.f;
#pragma unroll
      for (int kr = 0; kr < 14; ++kr) {
        float xr = t1R[kr * 8 + f], xi = t1I[kr * 8 + f];
        br += tc[kr] * xr - tsn[kr] * xi;
        bi += tc[kr] * xi + tsn[kr] * xr;
      }
      t2R[i] = br; t2I[i] = bi;
    }
    __syncthreads();
  };
  auto rowVal = [&](int r, int c) -> float {
    const float* pR = &t2R[r * 8]; const float* pI = &t2I[r * 8];
    float v = pR[0] + ((c & 1) ? -pR[7] : pR[7]);
    float s2 = 0.f;
#pragma unroll
    for (int f = 1; f < 7; ++f) s2 += pR[f] * TC[f * 14 + c] - pI[f] * TSn[f * 14 + c];
    return (v + 2.f * s2) * (1.0f / 196.0f);
  };

  for (int widx = blockIdx.x; widx < ntile; widx += gridDim.x) {
    const int tile = wl[widx];
    const int g = tile >> 5, b = tile & 31;
    __syncthreads();
    for (int i = t; i < 560; i += 64) {
      int ii = i / 112, p = i - ii * 112;
      const float* kp = kern + ((size_t)g * 5 + ii) * 224 + p * 2;
      kR[ii][p] = kp[0]; kI[ii][p] = kp[1];
    }
    for (int i = t; i < 196; i += 64) xs[i] = vxt[((size_t)b * DIMC + g) * 196 + i];
    for (int i = t; i < 112; i += 64) {
      k2R[i] = kern2[(size_t)g * 224 + i * 2];
      k2I[i] = kern2[(size_t)g * 224 + i * 2 + 1];
    }
    __syncthreads();

    rowsFwd(xs);
    colsFwd(zr, zi);
    for (int ii = 0; ii < 5; ++ii) {
      for (int i = t; i < 112; i += 64) {
        float a = kR[ii][i], b2 = kI[ii][i];
        t1R[i] = a * zr[i] - b2 * zi[i];
        t1I[i] = a * zi[i] + b2 * zr[i];
      }
      __syncthreads();
      colsInv();
      for (int i = t; i < 196; i += 64) uu[ii][i] = rowVal(i / 14, i - (i / 14) * 14);
      __syncthreads();
    }

    const float invL = 1.0f / Lbuf[g];
    const float thr = LAMC * invL;
    {
      float* up = &uu[0][0];
      float* sp = &ss[0][0];
      for (int i = t; i < 980; i += 64) {
        float v = up[i];
        float a = fabsf(v) - LAMC;
        sp[i] = a > 0.f ? copysignf(a, v) : 0.f;
      }
    }
    __syncthreads();

    for (int iter = 0; iter < 4; ++iter) {
      for (int i = t; i < 112; i += 64) { zr[i] = 0.f; zi[i] = 0.f; }
      __syncthreads();
      for (int ii = 0; ii < 5; ++ii) {
        rowsFwd(&ss[ii][0]);
        colsFwd(t2R, t2I);
        for (int i = t; i < 112; i += 64) {
          float a = kR[ii][i], b2 = kI[ii][i];
          zr[i] += a * t2R[i] + b2 * t2I[i];
          zi[i] += a * t2I[i] - b2 * t2R[i];
        }
        __syncthreads();
      }
      if (iter == 3) break;
      for (int ii = 0; ii < 5; ++ii) {
        for (int i = t; i < 112; i += 64) {
          float a = kR[ii][i], b2 = kI[ii][i];
          t1R[i] = a * zr[i] - b2 * zi[i];
          t1I[i] = a * zi[i] + b2 * zr[i];
        }
        __syncthreads();
        colsInv();
        for (int i = t; i < 196; i += 64) {
          float v = rowVal(i / 14, i - (i / 14) * 14);
          float sv = ss[ii][i] - (v - uu[ii][i]) * invL;
          float aa = fabsf(sv) - thr;
          ss[ii][i] = aa > 0.f ? copysignf(aa, sv) : 0.f;
        }
        __syncthreads();
      }
    }

    if (t < 28) {
      int kr = t >> 1, f = (t & 1) * 7;
      int d = kr * 8 + f;
      int srci = ((14 - kr) % 14) * 8 + f;
      float pr = 0.5f * (zr[d] + zr[srci]);
      float pi = 0.5f * (zi[d] - zi[srci]);
      zr[d] = pr; zi[d] = pi;
    }
    __syncthreads();
    for (int i = t; i < 112; i += 64) {
      float a = k2R[i], b2 = k2I[i];
      t1R[i] = a * zr[i] - b2 * zi[i];
      t1I[i] = a * zi[i] + b2 * zr[i];
    }
    __syncthreads();
    colsInv();
    for (int i = t; i < 196; i += 64)
      outp[((size_t)(b * 196 + i)) * DIMC + g] = rowVal(i / 14, i - (i / 14) * 14);
  }
}

// ---------------- launch ----------------
extern "C" void kernel_launch(void* const* d_in, const int* in_sizes, int n_in,
                              void* d_out, int out_size, void* d_ws, size_t ws_size,
                              hipStream_t stream) {
  (void)in_sizes; (void)n_in; (void)out_size;
  const float* x      = (const float*)d_in[0];
  const float* v_w    = (const float*)d_in[1];
  const float* proj_w = (const float*)d_in[2];
  const float* proj_b = (const float*)d_in[3];
  const float* kern   = (const float*)d_in[4];
  const float* kern2  = (const float*)d_in[5];
  const float* n1g    = (const float*)d_in[6];
  const float* n1b    = (const float*)d_in[7];
  const float* n2g    = (const float*)d_in[8];
  const float* n2b    = (const float*)d_in[9];
  const float* fc1w   = (const float*)d_in[10];
  const float* fc1b   = (const float*)d_in[11];
  const float* fc2w   = (const float*)d_in[12];
  const float* fc2b   = (const float*)d_in[13];
  const float* Lb     = (const float*)d_in[14];
  float* out = (float*)d_out;

  char* ws = (char*)d_ws;
  size_t o = 0;
  auto alloc = [&](size_t bytes) { size_t r = o; o += (bytes + 255) & ~(size_t)255; return r; };
  u16*   vwbf   = (u16*)(ws + alloc(589824 * 2));
  u16*   projbf = (u16*)(ws + alloc(589824 * 2));
  u16*   fc1bf  = (u16*)(ws + alloc(2359296 * 2));
  u16*   fc2bf  = (u16*)(ws + alloc(2359296 * 2));
  u16*   Ffb    = (u16*)(ws + alloc(50176 * 2));
  u16*   Gfb    = (u16*)(ws + alloc(46592 * 2));
  float* sc1    = (float*)(ws + alloc(768 * 4));
  float* sh1    = (float*)(ws + alloc(768 * 4));
  float* sc2    = (float*)(ws + alloc(768 * 4));
  float* sh2    = (float*)(ws + alloc(768 * 4));
  float* part   = (float*)(ws + alloc(98 * 768 * 2 * 4));
  int*   cnt    = (int*)(ws + alloc(4));
  int*   wl     = (int*)(ws + alloc(24576 * 4));
  u16*   abf    = (u16*)(ws + alloc((size_t)MTOT * DIMC * 2));
  float* vxt    = (float*)(ws + alloc((size_t)MTOT * DIMC * 4));
  float* newm   = (float*)(ws + alloc((size_t)MTOT * DIMC * 4));
  float* new2   = (float*)(ws + alloc((size_t)MTOT * DIMC * 4));
  u16*   pbf    = (u16*)(ws + alloc((size_t)4 * MTOT * DIMC * 2));  // split-K partials
  u16*   hbf    = (u16*)vxt;   // overlay: h (6272x3072 bf16) over vxt+newm (dead by then)
  if (ws_size < o) return;

  hipMemsetAsync(newm, 0, (size_t)MTOT * DIMC * 4, stream);
  hipMemsetAsync(cnt, 0, 4, stream);

  initfg_k<<<378, 256, 0, stream>>>(Ffb, Gfb);
  cvtw_k<<<5760, 256, 0, stream>>>(v_w, proj_w, fc1w, fc2w, vwbf, projbf, fc1bf, fc2bf);
  cvt4_k<<<4704, 256, 0, stream>>>(x, abf, 1204224);

  // vx = x @ v_w^T, transpose-written as (b, g, n)
  gemm_k<0><<<dim3(6, 49), 256, 0, stream>>>(abf, vwbf, nullptr, nullptr, vxt, DIMC, DIMC, DIMC);
  // MFMA screen -> worklist (newm stays zero for clean tiles)
  checkmfma_k<<<1536, 64, 0, stream>>>(vxt, kern, Ffb, Gfb, cnt, wl);
  // exact ISTA only for flagged tiles
  slow_k<<<1024, 64, 0, stream>>>(vxt, kern, kern2, Lb, cnt, wl, newm);
  // BN1
  stats_part_k<<<98, 256, 0, stream>>>(newm, part);
  stats_fin_k<<<3, 256, 0, stream>>>(part, n1g, n1b, sc1, sh1);
  bncvt_k<<<4704, 256, 0, stream>>>(newm, sc1, sh1, abf, 1204224);
  // new2 = x + BN1(new) @ proj_w^T + proj_b
  gemm_k<1><<<dim3(6, 49), 256, 0, stream>>>(abf, projbf, proj_b, x, new2, DIMC, DIMC, DIMC);
  // BN2
  stats_part_k<<<98, 256, 0, stream>>>(new2, part);
  stats_fin_k<<<3, 256, 0, stream>>>(part, n2g, n2b, sc2, sh2);
  bncvt_k<<<4704, 256, 0, stream>>>(new2, sc2, sh2, abf, 1204224);
  // h = gelu(BN2(new2) @ fc1^T + fc1_b)
  gemm_k<2><<<dim3(24, 49), 256, 0, stream>>>(abf, fc1bf, fc1b, nullptr, hbf, HIDC, DIMC, DIMC);
  // out = new2 + h @ fc2^T + fc2_b   (split-K=4, bf16 partials + reduce)
  gemm_k<3, 1><<<dim3(6, 49, 4), 256, 0, stream>>>(hbf, fc2bf, nullptr, nullptr, pbf, DIMC, 768, HIDC);
  redc_k<<<4704, 256, 0, stream>>>(pbf, fc2b, new2, out);
}

// Round 5
// 362.107 us; speedup vs baseline: 1.0088x; 1.0088x over previous
//
#include <hip/hip_runtime.h>
#include <cmath>

typedef unsigned short u16;
typedef __bf16 bf16x8 __attribute__((ext_vector_type(8)));
typedef float f32x4 __attribute__((ext_vector_type(4)));
typedef float float4v __attribute__((ext_vector_type(4)));
typedef u16 ushort4v __attribute__((ext_vector_type(4)));
typedef u16 ushort8v __attribute__((ext_vector_type(8)));

#define DIMC 768
#define NP 196
#define MTOT 6272         // 32*196
#define HIDC 3072
#define LAMC 3.5f

__device__ const float C14d[14] = {
  1.0f, 0.9009688679024191f, 0.6234898018587336f, 0.22252093395631445f,
  -0.22252093395631445f, -0.6234898018587336f, -0.9009688679024191f, -1.0f,
  -0.9009688679024191f, -0.6234898018587336f, -0.22252093395631445f,
  0.22252093395631445f, 0.6234898018587336f, 0.9009688679024191f
};
__device__ const float S14d[14] = {
  0.0f, 0.43388373911755823f, 0.7818314824680298f, 0.9749279121818236f,
  0.9749279121818236f, 0.7818314824680298f, 0.43388373911755823f, 0.0f,
  -0.43388373911755823f, -0.7818314824680298f, -0.9749279121818236f,
  -0.9749279121818236f, -0.7818314824680298f, -0.43388373911755823f
};

__device__ __forceinline__ u16 f2bf(float f) {
  unsigned u = __builtin_bit_cast(unsigned, f);
  unsigned r = u + 0x7FFFu + ((u >> 16) & 1u);
  return (u16)(r >> 16);
}
__device__ __forceinline__ float bf2f(u16 u) {
  return __builtin_bit_cast(float, (unsigned)u << 16);
}

typedef const __attribute__((address_space(1))) u16* gas_p;
typedef __attribute__((address_space(3))) u16* las_p;
__device__ __forceinline__ void gl16(const u16* g, u16* l) {
  __builtin_amdgcn_global_load_lds((gas_p)g, (las_p)l, 16, 0, 0);
}

// ---------------- build fragment-ordered DFT matrices F / G ----------------
__global__ __launch_bounds__(256) void initfg_k(u16* __restrict__ Ff, u16* __restrict__ Gf) {
  int idx = blockIdx.x * 256 + threadIdx.x;
  if (idx < 50176) {                       // Ff: 14*7*64*8
    int j = idx & 7, lane = (idx >> 3) & 63;
    int mk = idx >> 9, k0 = mk % 7, m0 = mk / 7;
    int s = m0 * 16 + (lane & 15);
    int q = k0 * 32 + (lane >> 4) * 8 + j;
    float v = 0.f;
    if (q < 196) {
      int kr = s >> 4, f = (s >> 1) & 7, r = q / 14, c = q % 14;
      int th = (kr * r + f * c) % 14;
      v = (s & 1) ? -S14d[th] : C14d[th];
    }
    Ff[idx] = f2bf(v);
  } else if (idx < 50176 + 46592) {        // Gf: 13*7*64*8
    int t = idx - 50176;
    int j = t & 7, lane = (t >> 3) & 63;
    int pk = t >> 9, k0 = pk % 7, p0 = pk / 7;
    int p = p0 * 16 + (lane & 15);
    int s = k0 * 32 + (lane >> 4) * 8 + j;
    float v = 0.f;
    if (p < 196) {
      int kr = s >> 4, f = (s >> 1) & 7, r = p / 14, c = p % 14;
      int th = (kr * r + f * c) % 14;
      float w = (f == 0 || f == 7) ? 1.f : 2.f;
      v = (w * (1.f / 196.f)) * ((s & 1) ? -S14d[th] : C14d[th]);
    }
    Gf[t] = f2bf(v);
  }
}

// ---------------- fused weight convert ----------------
__global__ __launch_bounds__(256) void cvtw_k(
    const float* __restrict__ w0, const float* __restrict__ w1,
    const float* __restrict__ w2, const float* __restrict__ w3,
    u16* __restrict__ o0, u16* __restrict__ o1,
    u16* __restrict__ o2, u16* __restrict__ o3) {
  int idx = blockIdx.x * 256 + threadIdx.x;
  const float* s; u16* d; int base;
  if (idx < 147456)      { s = w0; d = o0; base = 0; }
  else if (idx < 294912) { s = w1; d = o1; base = 147456; }
  else if (idx < 884736) { s = w2; d = o2; base = 294912; }
  else                   { s = w3; d = o3; base = 884736; }
  int i4 = (idx - base) * 4;
  float4v v = *(const float4v*)(s + i4);
  ushort4v o;
#pragma unroll
  for (int j = 0; j < 4; ++j) o[j] = f2bf(v[j]);
  *(ushort4v*)(d + i4) = o;
}

__global__ __launch_bounds__(256) void cvt4_k(const float* __restrict__ s,
                                              u16* __restrict__ d, int n4) {
  int idx = blockIdx.x * 256 + threadIdx.x;
  if (idx >= n4) return;
  int i4 = idx * 4;
  float4v v = *(const float4v*)(s + i4);
  ushort4v o;
#pragma unroll
  for (int j = 0; j < 4; ++j) o[j] = f2bf(v[j]);
  *(ushort4v*)(d + i4) = o;
}

// ---------------- BN-normalize + convert to bf16 ----------------
__global__ __launch_bounds__(256) void bncvt_k(const float* __restrict__ s,
    const float* __restrict__ sc, const float* __restrict__ sh,
    u16* __restrict__ d, int n4) {
  int idx = blockIdx.x * 256 + threadIdx.x;
  if (idx >= n4) return;
  int i4 = idx * 4;
  int c = i4 % DIMC;
  float4v v = *(const float4v*)(s + i4);
  float4v a = *(const float4v*)(sc + c);
  float4v b = *(const float4v*)(sh + c);
  v = v * a + b;
  ushort4v o;
#pragma unroll
  for (int j = 0; j < 4; ++j) o[j] = f2bf(v[j]);
  *(ushort4v*)(d + i4) = o;
}

// ---------------- 128x128 bf16 MFMA GEMM, dbuf pipeline, frag-ordered LDS ----
// T3-minimum 2-phase: prologue-stage buf0; per K-step issue next tile's
// global_load_lds into buf^1, then ds_read+MFMA on buf, then ONE barrier.
// Load latency hides under compute; one __syncthreads per iter.
// EPI 0: f32x4 transpose-write  vxt[(b*768+n)*196+np], m=b*196+np
// EPI 1: f32 C[m*Nr+n] = acc + bias[n] + res[m*Nr+n]
// EPI 2: bf16 C[m*Nr+n] = gelu_exact(acc + bias[n])
template<int EPI>
__global__ __launch_bounds__(256) void gemm_k(
    const u16* __restrict__ A, const u16* __restrict__ Bw,
    const float* __restrict__ bias, const float* __restrict__ res,
    void* __restrict__ Cp, int Nr, int Kr, int ld) {
  __shared__ __attribute__((aligned(16))) u16 As[2][128 * 32];
  __shared__ __attribute__((aligned(16))) u16 Bs[2][128 * 32];
  const int t = threadIdx.x;
  const int wid = t >> 6, lane = t & 63;
  const int bn = blockIdx.x * 128, bm = blockIdx.y * 128;
  const int wm = (wid >> 1) * 64, wn = (wid & 1) * 64;
  const int l15 = lane & 15, l4 = lane >> 4;

  f32x4 acc[4][4];
#pragma unroll
  for (int a = 0; a < 4; ++a)
#pragma unroll
    for (int b2 = 0; b2 < 4; ++b2) acc[a][b2] = (f32x4){0.f, 0.f, 0.f, 0.f};

  // fragment-order staging source (row = lane&15, kslot = lane>>4)
  const u16* gA0 = A + (size_t)(bm + wid * 16 + l15) * ld + l4 * 8;
  const u16* gB0 = Bw + (size_t)(bn + wid * 16 + l15) * ld + l4 * 8;

  auto STAGE = [&](int buf, int k0) {
    u16* lA = &As[buf][wid * 512];
    u16* lB = &Bs[buf][wid * 512];
    gl16(gA0 + k0, lA);
    gl16(gA0 + (size_t)64 * ld + k0, lA + 2048);
    gl16(gB0 + k0, lB);
    gl16(gB0 + (size_t)64 * ld + k0, lB + 2048);
  };

  STAGE(0, 0);
  __syncthreads();
  int cur = 0;

  for (int k0 = 0; k0 < Kr; k0 += 32) {
    if (k0 + 32 < Kr) STAGE(cur ^ 1, k0 + 32);

    bf16x8 af[4], bfv[4];
#pragma unroll
    for (int mb = 0; mb < 4; ++mb)
      af[mb] = *(const bf16x8*)&As[cur][((wid >> 1) * 4 + mb) * 512 + lane * 8];
#pragma unroll
    for (int nb = 0; nb < 4; ++nb)
      bfv[nb] = *(const bf16x8*)&Bs[cur][((wid & 1) * 4 + nb) * 512 + lane * 8];
#pragma unroll
    for (int mb = 0; mb < 4; ++mb)
#pragma unroll
      for (int nb = 0; nb < 4; ++nb)
        acc[mb][nb] = __builtin_amdgcn_mfma_f32_16x16x32_bf16(af[mb], bfv[nb], acc[mb][nb], 0, 0, 0);

    __syncthreads();          // drains staged loads (vmcnt0) + syncs buffers
    cur ^= 1;
  }

#pragma unroll
  for (int mb = 0; mb < 4; ++mb) {
#pragma unroll
    for (int nb = 0; nb < 4; ++nb) {
      int n = bn + wn + nb * 16 + l15;
      if (EPI == 0) {
        int m0 = bm + wm + mb * 16 + l4 * 4;
        int bb = m0 / 196, np0 = m0 - bb * 196;   // 4-aligned, same bb for r=0..3
        *(float4v*)&((float*)Cp)[((size_t)bb * DIMC + n) * 196 + np0] =
            (float4v){acc[mb][nb][0], acc[mb][nb][1], acc[mb][nb][2], acc[mb][nb][3]};
      } else {
#pragma unroll
        for (int r = 0; r < 4; ++r) {
          int m = bm + wm + mb * 16 + l4 * 4 + r;
          float v = acc[mb][nb][r];
          if (EPI == 1) {
            ((float*)Cp)[(size_t)m * Nr + n] = v + bias[n] + res[(size_t)m * Nr + n];
          } else {
            float vb = v + bias[n];
            float ge = 0.5f * vb * (1.f + erff(vb * 0.70710678118654752f));
            ((u16*)Cp)[(size_t)m * Nr + n] = f2bf(ge);
          }
        }
      }
    }
  }
}

// ---------------- BN stats (deterministic 2-stage) ----------------
__global__ __launch_bounds__(256) void stats_part_k(const float* __restrict__ A,
                                                    float* __restrict__ part) {
  int blk = blockIdx.x, t = threadIdx.x;
  float s0a = 0, s0b = 0, s0c = 0, s1a = 0, s1b = 0, s1c = 0;
  const float* base = A + (size_t)blk * 64 * DIMC;
  for (int r = 0; r < 64; ++r) {
    const float* row = base + (size_t)r * DIMC;
    float v0 = row[t], v1 = row[t + 256], v2 = row[t + 512];
    s0a += v0; s1a += v0 * v0;
    s0b += v1; s1b += v1 * v1;
    s0c += v2; s1c += v2 * v2;
  }
  part[(size_t)blk * DIMC + t] = s0a;
  part[(size_t)blk * DIMC + t + 256] = s0b;
  part[(size_t)blk * DIMC + t + 512] = s0c;
  float* p2 = part + 98 * DIMC;
  p2[(size_t)blk * DIMC + t] = s1a;
  p2[(size_t)blk * DIMC + t + 256] = s1b;
  p2[(size_t)blk * DIMC + t + 512] = s1c;
}

__global__ __launch_bounds__(256) void stats_fin_k(const float* __restrict__ part,
    const float* __restrict__ gam, const float* __restrict__ bet,
    float* __restrict__ scale, float* __restrict__ shift) {
  int c = blockIdx.x * 256 + threadIdx.x;
  if (c >= DIMC) return;
  float S = 0.f, Q = 0.f;
  for (int b = 0; b < 98; ++b) {
    S += part[(size_t)b * DIMC + c];
    Q += part[(size_t)(98 + b) * DIMC + c];
  }
  float m = S * (1.0f / 6272.0f);
  float v = Q * (1.0f / 6272.0f) - m * m;
  v = fmaxf(v, 0.f);
  float rs = rsqrtf(v + 1e-5f);
  float sc = gam[c] * rs;
  scale[c] = sc;
  shift[c] = bet[c] - m * sc;
}

// ---------------- MFMA screen: max_i max_p |u_i| per tile, flag > 3.4 ----------
__global__ __launch_bounds__(64) void checkmfma_k(
    const float* __restrict__ vxt, const float* __restrict__ kern,
    const u16* __restrict__ Ff, const u16* __restrict__ Gf,
    int* __restrict__ cnt, int* __restrict__ wl) {
  __shared__ float xf[16 * 228];
  const int lane = threadIdx.x;
  const int wgb = blockIdx.x;
  const int g = wgb >> 1, bhalf = wgb & 1;
  const int tl = lane & 15, h = lane >> 4;
  const float* xbase = vxt + ((size_t)(bhalf * 16 + tl) * DIMC + g) * 196;

  bf16x8 Bx[7];
#pragma unroll
  for (int k0 = 0; k0 < 7; ++k0) {
    int q0 = k0 * 32 + h * 8;
    ushort8v tv;
    if (k0 < 6) {
      float4v f0 = *(const float4v*)(xbase + q0);
      float4v f1 = *(const float4v*)(xbase + q0 + 4);
#pragma unroll
      for (int j = 0; j < 4; ++j) { tv[j] = f2bf(f0[j]); tv[j + 4] = f2bf(f1[j]); }
    } else {
#pragma unroll
      for (int j = 0; j < 8; ++j) {
        int q = q0 + j;
        tv[j] = (q < 196) ? f2bf(xbase[q]) : (u16)0;
      }
    }
    Bx[k0] = __builtin_bit_cast(bf16x8, tv);
  }

  for (int m0 = 0; m0 < 14; ++m0) {
    f32x4 acc = (f32x4){0.f, 0.f, 0.f, 0.f};
#pragma unroll
    for (int k0 = 0; k0 < 7; ++k0) {
      bf16x8 Af = __builtin_bit_cast(bf16x8,
          *(const ushort8v*)(Ff + ((size_t)(m0 * 7 + k0) * 64 + lane) * 8));
      acc = __builtin_amdgcn_mfma_f32_16x16x32_bf16(Af, Bx[k0], acc, 0, 0, 0);
    }
    *(f32x4*)&xf[tl * 228 + m0 * 16 + h * 4] = acc;
  }

  bf16x8 By[5][7];
#pragma unroll
  for (int i = 0; i < 5; ++i) {
    const float* kb = kern + ((size_t)g * 5 + i) * 224;
#pragma unroll
    for (int k0 = 0; k0 < 7; ++k0) {
      f32x4 x0 = *(const f32x4*)&xf[tl * 228 + k0 * 32 + h * 8];
      f32x4 x1 = *(const f32x4*)&xf[tl * 228 + k0 * 32 + h * 8 + 4];
      int mb = k0 * 16 + h * 4;
      float2 ka = *(const float2*)(kb + (mb + 0) * 2);
      float2 kc = *(const float2*)(kb + (mb + 1) * 2);
      float2 ke = *(const float2*)(kb + (mb + 2) * 2);
      float2 kg = *(const float2*)(kb + (mb + 3) * 2);
      ushort8v tv;
      tv[0] = f2bf(ka.x * x0[0] - ka.y * x0[1]);
      tv[1] = f2bf(ka.x * x0[1] + ka.y * x0[0]);
      tv[2] = f2bf(kc.x * x0[2] - kc.y * x0[3]);
      tv[3] = f2bf(kc.x * x0[3] + kc.y * x0[2]);
      tv[4] = f2bf(ke.x * x1[0] - ke.y * x1[1]);
      tv[5] = f2bf(ke.x * x1[1] + ke.y * x1[0]);
      tv[6] = f2bf(kg.x * x1[2] - kg.y * x1[3]);
      tv[7] = f2bf(kg.x * x1[3] + kg.y * x1[2]);
      By[i][k0] = __builtin_bit_cast(bf16x8, tv);
    }
  }

  float vmax = 0.f;
  for (int p0 = 0; p0 < 13; ++p0) {
    f32x4 a0 = (f32x4){0.f, 0.f, 0.f, 0.f};
    f32x4 a1 = a0, a2 = a0, a3 = a0, a4 = a0;
#pragma unroll
    for (int k0 = 0; k0 < 7; ++k0) {
      bf16x8 Ag = __builtin_bit_cast(bf16x8,
          *(const ushort8v*)(Gf + ((size_t)(p0 * 7 + k0) * 64 + lane) * 8));
      a0 = __builtin_amdgcn_mfma_f32_16x16x32_bf16(Ag, By[0][k0], a0, 0, 0, 0);
      a1 = __builtin_amdgcn_mfma_f32_16x16x32_bf16(Ag, By[1][k0], a1, 0, 0, 0);
      a2 = __builtin_amdgcn_mfma_f32_16x16x32_bf16(Ag, By[2][k0], a2, 0, 0, 0);
      a3 = __builtin_amdgcn_mfma_f32_16x16x32_bf16(Ag, By[3][k0], a3, 0, 0, 0);
      a4 = __builtin_amdgcn_mfma_f32_16x16x32_bf16(Ag, By[4][k0], a4, 0, 0, 0);
    }
#pragma unroll
    for (int r = 0; r < 4; ++r) {
      vmax = fmaxf(vmax, fabsf(a0[r]));
      vmax = fmaxf(vmax, fabsf(a1[r]));
      vmax = fmaxf(vmax, fabsf(a2[r]));
      vmax = fmaxf(vmax, fabsf(a3[r]));
      vmax = fmaxf(vmax, fabsf(a4[r]));
    }
  }
  vmax = fmaxf(vmax, __shfl_xor(vmax, 16));
  vmax = fmaxf(vmax, __shfl_xor(vmax, 32));
  if (lane < 16 && vmax > (LAMC - 0.1f)) {
    int idx = atomicAdd(cnt, 1);
    wl[idx] = g * 32 + bhalf * 16 + lane;
  }
}

// ---------------- full ISTA for flagged tiles (fp32, exact) ----------------
__global__ __launch_bounds__(64) void slow_k(
    const float* __restrict__ vxt, const float* __restrict__ kern,
    const float* __restrict__ kern2, const float* __restrict__ Lbuf,
    const int* __restrict__ cnt, const int* __restrict__ wl,
    float* __restrict__ outp) {
  const int t = threadIdx.x;
  __shared__ float TC[196], TSn[196];
  __shared__ float xs[196];
  __shared__ float t1R[112], t1I[112];
  __shared__ float t2R[112], t2I[112];
  __shared__ float zr[112], zi[112];
  __shared__ float kR[5][112], kI[5][112];
  __shared__ float uu[5][196];
  __shared__ float ss[5][196];
  __shared__ float k2R[112], k2I[112];

  for (int i = t; i < 196; i += 64) {
    int a = i / 14, c = i - (i / 14) * 14;
    int m = (a * c) % 14;
    TC[i] = C14d[m]; TSn[i] = S14d[m];
  }
  const int ntile = *cnt;

  auto rowsFwd = [&](const float* xsrc) {
    for (int i = t; i < 112; i += 64) {
      int r = i >> 3, f = i & 7;
      const float* xp = xsrc + r * 14;
      const float* tc = &TC[f * 14]; const float* tsn = &TSn[f * 14];
      float ar = 0.f, ai = 0.f;
#pragma unroll
      for (int c = 0; c < 14; ++c) { float xv = xp[c]; ar += xv * tc[c]; ai -= xv * tsn[c]; }
      t1R[i] = ar; t1I[i] = ai;
    }
    __syncthreads();
  };
  auto colsFwd = [&](float* oR, float* oI) {
    for (int i = t; i < 112; i += 64) {
      int kr = i >> 3, f = i & 7;
      const float* tc = &TC[kr * 14]; const float* tsn = &TSn[kr * 14];
      float br = 0.f, bi = 0.f;
#pragma unroll
      for (int r = 0; r < 14; ++r) {
        float xr = t1R[r * 8 + f], xi = t1I[r * 8 + f];
        br += tc[r] * xr + tsn[r] * xi;
        bi += tc[r] * xi - tsn[r] * xr;
      }
      oR[i] = br; oI[i] = bi;
    }
    __syncthreads();
  };
  auto colsInv = [&]() {
    for (int i = t; i < 112; i += 64) {
      int r = i >> 3, f = i & 7;
      const float* tc = &TC[r * 14]; const float* tsn = &TSn[r * 14];
      float br = 0.f, bi = 0.f;
#pragma unroll
      for (int kr = 0; kr < 14; ++kr) {
        float xr = t1R[kr * 8 + f], xi = t1I[kr * 8 + f];
        br += tc[kr] * xr - tsn[kr] * xi;
        bi += tc[kr] * xi + tsn[kr] * xr;
      }
      t2R[i] = br; t2I[i] = bi;
    }
    __syncthreads();
  };
  auto rowVal = [&](int r, int c) -> float {
    const float* pR = &t2R[r * 8]; const float* pI = &t2I[r * 8];
    float v = pR[0] + ((c & 1) ? -pR[7] : pR[7]);
    float s2 = 0.f;
#pragma unroll
    for (int f = 1; f < 7; ++f) s2 += pR[f] * TC[f * 14 + c] - pI[f] * TSn[f * 14 + c];
    return (v + 2.f * s2) * (1.0f / 196.0f);
  };

  for (int widx = blockIdx.x; widx < ntile; widx += gridDim.x) {
    const int tile = wl[widx];
    const int g = tile >> 5, b = tile & 31;
    __syncthreads();
    for (int i = t; i < 560; i += 64) {
      int ii = i / 112, p = i - ii * 112;
      const float* kp = kern + ((size_t)g * 5 + ii) * 224 + p * 2;
      kR[ii][p] = kp[0]; kI[ii][p] = kp[1];
    }
    for (int i = t; i < 196; i += 64) xs[i] = vxt[((size_t)b * DIMC + g) * 196 + i];
    for (int i = t; i < 112; i += 64) {
      k2R[i] = kern2[(size_t)g * 224 + i * 2];
      k2I[i] = kern2[(size_t)g * 224 + i * 2 + 1];
    }
    __syncthreads();

    rowsFwd(xs);
    colsFwd(zr, zi);
    for (int ii = 0; ii < 5; ++ii) {
      for (int i = t; i < 112; i += 64) {
        float a = kR[ii][i], b2 = kI[ii][i];
        t1R[i] = a * zr[i] - b2 * zi[i];
        t1I[i] = a * zi[i] + b2 * zr[i];
      }
      __syncthreads();
      colsInv();
      for (int i = t; i < 196; i += 64) uu[ii][i] = rowVal(i / 14, i - (i / 14) * 14);
      __syncthreads();
    }

    const float invL = 1.0f / Lbuf[g];
    const float thr = LAMC * invL;
    {
      float* up = &uu[0][0];
      float* sp = &ss[0][0];
      for (int i = t; i < 980; i += 64) {
        float v = up[i];
        float a = fabsf(v) - LAMC;
        sp[i] = a > 0.f ? copysignf(a, v) : 0.f;
      }
    }
    __syncthreads();

    for (int iter = 0; iter < 4; ++iter) {
      for (int i = t; i < 112; i += 64) { zr[i] = 0.f; zi[i] = 0.f; }
      __syncthreads();
      for (int ii = 0; ii < 5; ++ii) {
        rowsFwd(&ss[ii][0]);
        colsFwd(t2R, t2I);
        for (int i = t; i < 112; i += 64) {
          float a = kR[ii][i], b2 = kI[ii][i];
          zr[i] += a * t2R[i] + b2 * t2I[i];
          zi[i] += a * t2I[i] - b2 * t2R[i];
        }
        __syncthreads();
      }
      if (iter == 3) break;
      for (int ii = 0; ii < 5; ++ii) {
        for (int i = t; i < 112; i += 64) {
          float a = kR[ii][i], b2 = kI[ii][i];
          t1R[i] = a * zr[i] - b2 * zi[i];
          t1I[i] = a * zi[i] + b2 * zr[i];
        }
        __syncthreads();
        colsInv();
        for (int i = t; i < 196; i += 64) {
          float v = rowVal(i / 14, i - (i / 14) * 14);
          float sv = ss[ii][i] - (v - uu[ii][i]) * invL;
          float aa = fabsf(sv) - thr;
          ss[ii][i] = aa > 0.f ? copysignf(aa, sv) : 0.f;
        }
        __syncthreads();
      }
    }

    if (t < 28) {
      int kr = t >> 1, f = (t & 1) * 7;
      int d = kr * 8 + f;
      int srci = ((14 - kr) % 14) * 8 + f;
      float pr = 0.5f * (zr[d] + zr[srci]);
      float pi = 0.5f * (zi[d] - zi[srci]);
      zr[d] = pr; zi[d] = pi;
    }
    __syncthreads();
    for (int i = t; i < 112; i += 64) {
      float a = k2R[i], b2 = k2I[i];
      t1R[i] = a * zr[i] - b2 * zi[i];
      t1I[i] = a * zi[i] + b2 * zr[i];
    }
    __syncthreads();
    colsInv();
    for (int i = t; i < 196; i += 64)
      outp[((size_t)(b * 196 + i)) * DIMC + g] = rowVal(i / 14, i - (i / 14) * 14);
  }
}

// ---------------- launch ----------------
extern "C" void kernel_launch(void* const* d_in, const int* in_sizes, int n_in,
                              void* d_out, int out_size, void* d_ws, size_t ws_size,
                              hipStream_t stream) {
  (void)in_sizes; (void)n_in; (void)out_size;
  const float* x      = (const float*)d_in[0];
  const float* v_w    = (const float*)d_in[1];
  const float* proj_w = (const float*)d_in[2];
  const float* proj_b = (const float*)d_in[3];
  const float* kern   = (const float*)d_in[4];
  const float* kern2  = (const float*)d_in[5];
  const float* n1g    = (const float*)d_in[6];
  const float* n1b    = (const float*)d_in[7];
  const float* n2g    = (const float*)d_in[8];
  const float* n2b    = (const float*)d_in[9];
  const float* fc1w   = (const float*)d_in[10];
  const float* fc1b   = (const float*)d_in[11];
  const float* fc2w   = (const float*)d_in[12];
  const float* fc2b   = (const float*)d_in[13];
  const float* Lb     = (const float*)d_in[14];
  float* out = (float*)d_out;

  char* ws = (char*)d_ws;
  size_t o = 0;
  auto alloc = [&](size_t bytes) { size_t r = o; o += (bytes + 255) & ~(size_t)255; return r; };
  u16*   vwbf   = (u16*)(ws + alloc(589824 * 2));
  u16*   projbf = (u16*)(ws + alloc(589824 * 2));
  u16*   fc1bf  = (u16*)(ws + alloc(2359296 * 2));
  u16*   fc2bf  = (u16*)(ws + alloc(2359296 * 2));
  u16*   Ffb    = (u16*)(ws + alloc(50176 * 2));
  u16*   Gfb    = (u16*)(ws + alloc(46592 * 2));
  float* sc1    = (float*)(ws + alloc(768 * 4));
  float* sh1    = (float*)(ws + alloc(768 * 4));
  float* sc2    = (float*)(ws + alloc(768 * 4));
  float* sh2    = (float*)(ws + alloc(768 * 4));
  float* part   = (float*)(ws + alloc(98 * 768 * 2 * 4));
  int*   cnt    = (int*)(ws + alloc(4));
  int*   wl     = (int*)(ws + alloc(24576 * 4));
  u16*   abf    = (u16*)(ws + alloc((size_t)MTOT * DIMC * 2));
  float* vxt    = (float*)(ws + alloc((size_t)MTOT * DIMC * 4));
  float* newm   = (float*)(ws + alloc((size_t)MTOT * DIMC * 4));
  float* new2   = (float*)(ws + alloc((size_t)MTOT * DIMC * 4));
  u16*   hbf    = (u16*)vxt;   // overlay: h (6272x3072 bf16) over vxt+newm (dead by then)
  if (ws_size < o) return;

  hipMemsetAsync(newm, 0, (size_t)MTOT * DIMC * 4, stream);
  hipMemsetAsync(cnt, 0, 4, stream);

  initfg_k<<<378, 256, 0, stream>>>(Ffb, Gfb);
  cvtw_k<<<5760, 256, 0, stream>>>(v_w, proj_w, fc1w, fc2w, vwbf, projbf, fc1bf, fc2bf);
  cvt4_k<<<4704, 256, 0, stream>>>(x, abf, 1204224);

  // vx = x @ v_w^T, transpose-written as (b, g, n)
  gemm_k<0><<<dim3(6, 49), 256, 0, stream>>>(abf, vwbf, nullptr, nullptr, vxt, DIMC, DIMC, DIMC);
  // MFMA screen -> worklist (newm stays zero for clean tiles)
  checkmfma_k<<<1536, 64, 0, stream>>>(vxt, kern, Ffb, Gfb, cnt, wl);
  // exact ISTA only for flagged tiles
  slow_k<<<1024, 64, 0, stream>>>(vxt, kern, kern2, Lb, cnt, wl, newm);
  // BN1
  stats_part_k<<<98, 256, 0, stream>>>(newm, part);
  stats_fin_k<<<3, 256, 0, stream>>>(part, n1g, n1b, sc1, sh1);
  bncvt_k<<<4704, 256, 0, stream>>>(newm, sc1, sh1, abf, 1204224);
  // new2 = x + BN1(new) @ proj_w^T + proj_b
  gemm_k<1><<<dim3(6, 49), 256, 0, stream>>>(abf, projbf, proj_b, x, new2, DIMC, DIMC, DIMC);
  // BN2
  stats_part_k<<<98, 256, 0, stream>>>(new2, part);
  stats_fin_k<<<3, 256, 0, stream>>>(part, n2g, n2b, sc2, sh2);
  bncvt_k<<<4704, 256, 0, stream>>>(new2, sc2, sh2, abf, 1204224);
  // h = gelu(BN2(new2) @ fc1^T + fc1_b)
  gemm_k<2><<<dim3(24, 49), 256, 0, stream>>>(abf, fc1bf, fc1b, nullptr, hbf, HIDC, DIMC, DIMC);
  // out = new2 + h @ fc2^T + fc2_b
  gemm_k<1><<<dim3(6, 49), 256, 0, stream>>>(hbf, fc2bf, fc2b, new2, out, DIMC, HIDC, HIDC);
}